// Round 3
// baseline (980.303 us; speedup 1.0000x reference)
//
#include <hip/hip_runtime.h>
#include <math.h>

// VGAE forward: 3x GCNConv + reparameterize.
// Pipeline: bucket-sort CSR build (bhist/bscan/bucket/fill2) -> MFMA GEMM1
//           (dis-scaled, f16 out) -> agg1(+b1,relu,f16) -> MFMA GEMM2
//           (W_mu|W_lv fused, dis-scaled, f16) -> agg2 (f32 + fused z).
// R2: hierarchical scan. R3: 16-bit intermediates, dis pre-scaled in GEMM.
// R4: scatter-free bucket-sort CSR build. R5: MFMA GEMM, W in VGPR B-frags.
// R6: k_bucket de-spilled; k_agg 16B-lane gather; k_final fused into agg2.
// R7: segment-blocked aggregation. fill2 seg-sorts each node's srcs by
//     source segment (8192 nodes = 2MB of F per seg) and emits per-node seg
//     boundaries nsp[n][s]. k_agg runs exactly-resident 8192 waves, 13 nodes
//     per wave in register accumulators, sweeping segments in a common outer
//     loop -> gather working set ~2MB/XCD -> L2-resident (was 191MB L2-miss
//     traffic per agg at ~2.5 TB/s = the measured wall).
// R7b: NT stores via clang ext-vector f32x2 (HIP float2 class rejected).

#define SHIFT 9            // nodes per bucket = 512
#define EPB 2048           // edges per k_bucket block
#define HEPB 8192          // edges per k_bhist block

#define SEG_SHIFT 13       // source segment = 8192 nodes = 2MB of f16[128]
#define NSEG 13            // ceil(100000 / 8192)
#define NSP_STRIDE 16      // nsp ints per node (NSEG+1 padded)
#define KNODES 13          // nodes per wave in k_agg
#define AGG_BLOCKS 2048    // 8192 waves: exactly co-resident at 8 blk/CU

using f32x4 = __attribute__((ext_vector_type(4))) float;
using f32x2 = __attribute__((ext_vector_type(2))) float;
using f16x8 = __attribute__((ext_vector_type(8))) _Float16;
using f16x2 = __attribute__((ext_vector_type(2))) _Float16;

// Block-wide (256 thr) exclusive scan of one int per thread.
__device__ inline int scan256(int v, int* wsum) {
    __syncthreads();  // protect wsum reuse across calls
    int lane = threadIdx.x & 63, wid = threadIdx.x >> 6;
    int s = v;
#pragma unroll
    for (int d = 1; d < 64; d <<= 1) {
        int u = __shfl_up(s, d, 64);
        if (lane >= d) s += u;
    }
    if (lane == 63) wsum[wid] = s;
    __syncthreads();
    int off = 0;
    for (int w = 0; w < wid; w++) off += wsum[w];
    return off + s - v;
}

// Per-block LDS histogram of bucket ids -> global bucket histogram.
__global__ __launch_bounds__(256) void k_bhist(const int* __restrict__ coli,
                                               int* __restrict__ gbh,
                                               int E, int NB) {
    __shared__ int lh[4][256];
    int t = threadIdx.x, w = t >> 6;
    lh[0][t] = 0; lh[1][t] = 0; lh[2][t] = 0; lh[3][t] = 0;
    __syncthreads();
    int base = blockIdx.x * HEPB;
    for (int i = t; i < HEPB; i += 256) {
        int e = base + i;
        if (e < E) atomicAdd(&lh[w][coli[e] >> SHIFT], 1);
    }
    __syncthreads();
    if (t < NB) {
        int v = lh[0][t] + lh[1][t] + lh[2][t] + lh[3][t];
        if (v) atomicAdd(&gbh[t], v);
    }
}

// One block: scan bucket sums -> bucketptr + cursors.
__global__ __launch_bounds__(256) void k_bscan(const int* __restrict__ gbh,
                                               int* __restrict__ bptr,
                                               int* __restrict__ bcur,
                                               int NB, int E) {
    __shared__ int wsum[4];
    int t = threadIdx.x;
    int v = (t < NB) ? gbh[t] : 0;
    int e = scan256(v, wsum);
    if (t < NB) { bptr[t] = e; bcur[t] = e; }
    if (t == 0) bptr[NB] = E;
}

// Bin EPB edges into LDS by bucket, burst-write (row,col) records to
// contiguous per-bucket runs. Two passes over the (L2-hot) chunk; per-wave
// histograms + cursors (4x) cut LDS-atomic contention.
__global__ __launch_bounds__(256) void k_bucket(const int* __restrict__ rowi,
                                                const int* __restrict__ coli,
                                                int* __restrict__ bcur,
                                                int2* __restrict__ recs,
                                                int E, int NB) {
    __shared__ int lh[4][256], lcur[4][256], excl[256], gbase[256], wsum[4];
    __shared__ int2 stage[EPB];
    int t = threadIdx.x, w = t >> 6;
    lh[0][t] = 0; lh[1][t] = 0; lh[2][t] = 0; lh[3][t] = 0;
    __syncthreads();
    int base = blockIdx.x * EPB;
    int nE = min(EPB, E - base);
    // pass A: per-wave histogram
    for (int i = t; i < nE; i += 256)
        atomicAdd(&lh[w][coli[base + i] >> SHIFT], 1);
    __syncthreads();
    int h0 = lh[0][t], h1 = lh[1][t], h2 = lh[2][t], h3 = lh[3][t];
    int tot = h0 + h1 + h2 + h3;
    int ex = scan256(tot, wsum);
    excl[t] = ex;
    lcur[0][t] = ex;
    lcur[1][t] = ex + h0;
    lcur[2][t] = ex + h0 + h1;
    lcur[3][t] = ex + h0 + h1 + h2;
    if (t < NB && tot) gbase[t] = atomicAdd(&bcur[t], tot);
    __syncthreads();
    // pass B: re-read (L2-hot) and scatter into LDS stage, per-wave cursors
    for (int i = t; i < nE; i += 256) {
        int r = rowi[base + i], c = coli[base + i];
        int p = atomicAdd(&lcur[w][c >> SHIFT], 1);
        stage[p] = make_int2(r, c);
    }
    __syncthreads();
    // pass C: coalesced burst write per bucket run
    for (int i = t; i < nE; i += 256) {
        int2 r = stage[i];
        int bb = r.y >> SHIFT;
        recs[gbase[bb] + (i - excl[bb])] = r;
    }
}

// One block per bucket: per-(node,seg) histogram -> nsp (per-node segment
// boundaries, seg = src>>SEG_SHIFT) + dis; then seg-sorted scatter of srcs
// (direct global, within the bucket's ~32KB window -> L2-absorbed).
__global__ __launch_bounds__(256) void k_fill2(const int2* __restrict__ recs,
                                               const int* __restrict__ bptr,
                                               int* __restrict__ nsp,
                                               float* __restrict__ dis,
                                               int* __restrict__ srcs, int N) {
    __shared__ int hist[512 * NSEG];   // 26.6 KB
    __shared__ int excl[512 * NSEG];   // 26.6 KB
    __shared__ int wsum[4];
    int t = threadIdx.x;
    int b = blockIdx.x;
    int nbase = b << SHIFT;
    int start = bptr[b], end = bptr[b + 1];
    for (int i = t; i < 512 * NSEG; i += 256) hist[i] = 0;
    __syncthreads();
    for (int i = start + t; i < end; i += 256) {
        int2 r = recs[i];
        atomicAdd(&hist[(r.y - nbase) * NSEG + (r.x >> SEG_SHIFT)], 1);
    }
    __syncthreads();
    int n0 = 2 * t, n1 = 2 * t + 1;
    int tot0 = 0, tot1 = 0;
#pragma unroll
    for (int s = 0; s < NSEG; s++) {
        tot0 += hist[n0 * NSEG + s];
        tot1 += hist[n1 * NSEG + s];
    }
    int e0 = scan256(tot0 + tot1, wsum);
    int g0 = nbase + n0, g1 = nbase + n1;
    if (g0 < N) dis[g0] = rsqrtf((float)(tot0 + 1));
    if (g1 < N) dis[g1] = rsqrtf((float)(tot1 + 1));
    int c = start + e0;
#pragma unroll
    for (int s = 0; s < NSEG; s++) {
        if (g0 < N) nsp[g0 * NSP_STRIDE + s] = c;
        excl[n0 * NSEG + s] = c;
        c += hist[n0 * NSEG + s];
    }
    if (g0 < N) nsp[g0 * NSP_STRIDE + NSEG] = c;
#pragma unroll
    for (int s = 0; s < NSEG; s++) {
        if (g1 < N) nsp[g1 * NSP_STRIDE + s] = c;
        excl[n1 * NSEG + s] = c;
        c += hist[n1 * NSEG + s];
    }
    if (g1 < N) nsp[g1 * NSP_STRIDE + NSEG] = c;
    __syncthreads();
    for (int i = start + t; i < end; i += 256) {
        int2 r = recs[i];
        int p = atomicAdd(&excl[(r.y - nbase) * NSEG + (r.x >> SEG_SHIFT)], 1);
        srcs[p] = r.x;
    }
}

// Y[M,128] = dis[row] * (X[M,128] @ W[128,128]) -> f16, via MFMA 16x16x32.
// W cols [0,split) from Wa (f32, row stride split), [split,128) from Wb.
// W staged swizzled in LDS then hoisted into 32 f16x8 VGPR B-frags.
// Verified layouts (learn_hip m89/m120):
//   A[m=lane&15][k=quad*8+j], B[k=quad*8+j][n=lane&15],
//   C/D col=lane&15 row=quad*4+reg.
template <bool XF16>
__global__ __launch_bounds__(256) void k_gemm(const void* __restrict__ Xv,
                                              const float* __restrict__ Wa,
                                              const float* __restrict__ Wb,
                                              int split,
                                              const float* __restrict__ dis,
                                              _Float16* __restrict__ Y,
                                              int M, int ngroups) {
    __shared__ _Float16 Wl[16384];  // 32 KB swizzled
    int tid = threadIdx.x;
    int wbs = 128 - split;
    for (int i = tid; i < 16384; i += 256) {
        int k = i >> 7, n = i & 127;
        float v = (n < split) ? Wa[k * split + n] : Wb[k * wbs + (n - split)];
        int tt = n >> 4, c = (k >> 5), q = (k >> 3) & 3, ln = q * 16 + (n & 15);
        Wl[(((tt * 4 + c) * 64) + ln) * 8 + (k & 7)] = (_Float16)v;
    }
    __syncthreads();

    int lane = tid & 63, w = tid >> 6;
    f16x8 B[32];
#pragma unroll
    for (int i = 0; i < 32; i++)
        B[i] = *(const f16x8*)&Wl[(i * 64 + lane) * 8];

    int m16 = lane & 15, quad = lane >> 4;
    for (int g = blockIdx.x; g < ngroups; g += gridDim.x) {
        int rowbase = g * 64 + w * 16;
        if (rowbase >= M) continue;
        int arow = min(rowbase + m16, M - 1);
        f16x8 A[4];
        if (XF16) {
            const _Float16* X = (const _Float16*)Xv;
#pragma unroll
            for (int c = 0; c < 4; c++)
                A[c] = *(const f16x8*)&X[arow * 128 + c * 32 + quad * 8];
        } else {
            const float* X = (const float*)Xv;
#pragma unroll
            for (int c = 0; c < 4; c++) {
                float4 u0 = *(const float4*)&X[arow * 128 + c * 32 + quad * 8];
                float4 u1 = *(const float4*)&X[arow * 128 + c * 32 + quad * 8 + 4];
                f16x8 a;
                a[0] = (_Float16)u0.x; a[1] = (_Float16)u0.y;
                a[2] = (_Float16)u0.z; a[3] = (_Float16)u0.w;
                a[4] = (_Float16)u1.x; a[5] = (_Float16)u1.y;
                a[6] = (_Float16)u1.z; a[7] = (_Float16)u1.w;
                A[c] = a;
            }
        }

        f32x4 acc[8];
#pragma unroll
        for (int t = 0; t < 8; t++) acc[t] = (f32x4)(0.f);
#pragma unroll
        for (int t = 0; t < 8; t++)
#pragma unroll
            for (int c = 0; c < 4; c++)
                acc[t] = __builtin_amdgcn_mfma_f32_16x16x32_f16(
                    A[c], B[t * 4 + c], acc[t], 0, 0, 0);

#pragma unroll
        for (int r = 0; r < 4; r++) {
            int row = rowbase + quad * 4 + r;
            if (row < M) {
                float d = dis[row];
#pragma unroll
                for (int t = 0; t < 8; t++)
                    Y[row * 128 + t * 16 + m16] = (_Float16)(d * acc[t][r]);
            }
        }
    }
}

// Segment-blocked aggregation. F is dis-prescaled f16 [N,128].
// 8192 waves (exactly co-resident), KNODES nodes/wave, f32 accumulators in
// registers (statically indexed). Outer loop over source segments: all
// resident waves gather from the same ~2MB slice of F at a time -> L2 hits.
// Self term is added in the node's own segment. Epilogue:
//  OF16: h = relu(di*acc + b) -> f16 [N,128].
//  else: mu -> outA, lv -> outB (f32 [N,64]), z = mu + eps*exp(0.5 lv) fused
//        (lanes<32 hold mu cols, lanes>=32 hold lv cols; pair via shfl_xor 32).
template <bool OF16>
__global__ __launch_bounds__(256) void k_agg(const _Float16* __restrict__ F,
                                             const float* __restrict__ dis,
                                             const int* __restrict__ nsp,
                                             const int* __restrict__ srcs,
                                             const float* __restrict__ ba,
                                             const float* __restrict__ bb,
                                             void* __restrict__ outA,
                                             void* __restrict__ outB,
                                             const float* __restrict__ eps,
                                             float* __restrict__ z, int N) {
    int wv = blockIdx.x * 4 + (threadIdx.x >> 6);
    int lane = threadIdx.x & 63;
    int base = wv * KNODES;
    const f16x2* Fv = (const f16x2*)F;

    float ax[KNODES], ay[KNODES];
    int cur[KNODES];
#pragma unroll
    for (int n = 0; n < KNODES; n++) {
        ax[n] = 0.f;
        ay[n] = 0.f;
        int node = base + n;
        cur[n] = (node < N) ? nsp[node * NSP_STRIDE] : 0;
    }

#pragma unroll 1
    for (int s = 0; s < NSEG; s++) {
#pragma unroll
        for (int n = 0; n < KNODES; n++) {
            int node = base + n;
            if (node >= N) continue;
            int nxt = nsp[node * NSP_STRIDE + s + 1];
            if ((node >> SEG_SHIFT) == s) {  // self term lives in this seg
                f16x2 v = Fv[node * 64 + lane];
                ax[n] += (float)v[0];
                ay[n] += (float)v[1];
            }
            int t = cur[n];
            for (; t + 2 <= nxt; t += 2) {
                int s0 = srcs[t], s1 = srcs[t + 1];
                f16x2 v0 = Fv[s0 * 64 + lane];
                f16x2 v1 = Fv[s1 * 64 + lane];
                ax[n] += (float)v0[0] + (float)v1[0];
                ay[n] += (float)v0[1] + (float)v1[1];
            }
            if (t < nxt) {
                int s0 = srcs[t];
                f16x2 v0 = Fv[s0 * 64 + lane];
                ax[n] += (float)v0[0];
                ay[n] += (float)v0[1];
            }
            cur[n] = nxt;
        }
    }

    if constexpr (OF16) {
        float bx = ba[2 * lane], by = ba[2 * lane + 1];
#pragma unroll
        for (int n = 0; n < KNODES; n++) {
            int node = base + n;
            if (node >= N) continue;
            float di = dis[node];
            f16x2 o;
            o[0] = (_Float16)fmaxf(fmaf(di, ax[n], bx), 0.f);
            o[1] = (_Float16)fmaxf(fmaf(di, ay[n], by), 0.f);
            ((f16x2*)outA)[node * 64 + lane] = o;
        }
    } else {
        bool isMu = lane < 32;
        int cb = isMu ? 2 * lane : 2 * lane - 64;
        const float* bp = isMu ? ba : bb;
        float bx = bp[cb], by = bp[cb + 1];
        float* op = isMu ? (float*)outA : (float*)outB;
#pragma unroll
        for (int n = 0; n < KNODES; n++) {
            int node = base + n;
            if (node >= N) continue;
            float di = dis[node];
            float ox = fmaf(di, ax[n], bx);
            float oy = fmaf(di, ay[n], by);
            f32x2 ov;
            ov[0] = ox; ov[1] = oy;
            __builtin_nontemporal_store(ov, (f32x2*)&op[node * 64 + cb]);
            float lx = __shfl_xor(ox, 32);  // lane<32 pulls lv of same cols
            float ly = __shfl_xor(oy, 32);
            if (isMu) {
                float2 e = *(const float2*)&eps[node * 64 + cb];
                f32x2 zv;
                zv[0] = fmaf(e.x, expf(0.5f * lx), ox);
                zv[1] = fmaf(e.y, expf(0.5f * ly), oy);
                __builtin_nontemporal_store(zv, (f32x2*)&z[node * 64 + cb]);
            }
        }
    }
}

extern "C" void kernel_launch(void* const* d_in, const int* in_sizes, int n_in,
                              void* d_out, int out_size, void* d_ws, size_t ws_size,
                              hipStream_t stream) {
    const float* x   = (const float*)d_in[0];
    const int*   ei  = (const int*)d_in[1];
    const float* W1  = (const float*)d_in[2];
    const float* b1  = (const float*)d_in[3];
    const float* Wmu = (const float*)d_in[4];
    const float* bmu = (const float*)d_in[5];
    const float* Wlv = (const float*)d_in[6];
    const float* blv = (const float*)d_in[7];
    const float* eps = (const float*)d_in[8];

    int N = in_sizes[0] / 128;   // 100000
    int E = in_sizes[1] / 2;     // 1600000
    const int* rowi = ei;        // edge_index[0]
    const int* coli = ei + E;    // edge_index[1]
    int NB = (N + (1 << SHIFT) - 1) >> SHIFT;   // 196 buckets

    char* ws = (char*)d_ws;
    size_t off = 0;
    auto alloc = [&](size_t bytes) -> void* {
        void* p = ws + off;
        off += (bytes + 255) & ~(size_t)255;
        return p;
    };
    _Float16* bufA = (_Float16*)alloc((size_t)N * 128 * 2);  // F'1, F'2
    _Float16* bufB = (_Float16*)alloc((size_t)N * 128 * 2);  // h (f16)
    float* dis    = (float*)alloc((size_t)N * 4);
    int*   nsp    = (int*)alloc((size_t)N * NSP_STRIDE * 4); // seg boundaries
    int*   srcs   = (int*)alloc((size_t)E * 4);
    int2*  recs   = (int2*)alloc((size_t)E * 8);
    int*   bhist  = (int*)alloc((size_t)NB * 4);
    int*   bptr   = (int*)alloc((size_t)(NB + 1) * 4);
    int*   bcur   = (int*)alloc((size_t)NB * 4);

    float* zo  = (float*)d_out;                 // [N,64]
    float* muo = zo + (size_t)N * 64;           // [N,64]
    float* lvo = zo + (size_t)N * 128;          // [N,64]

    hipMemsetAsync(bhist, 0, (size_t)NB * 4, stream);
    k_bhist<<<(E + HEPB - 1) / HEPB, 256, 0, stream>>>(coli, bhist, E, NB);
    k_bscan<<<1, 256, 0, stream>>>(bhist, bptr, bcur, NB, E);
    k_bucket<<<(E + EPB - 1) / EPB, 256, 0, stream>>>(rowi, coli, bcur, recs, E, NB);
    k_fill2<<<NB, 256, 0, stream>>>(recs, bptr, nsp, dis, srcs, N);

    int ngroups = (N + 63) / 64;
    int gblk = ngroups < 640 ? ngroups : 640;
    // F'1 = dis . (x @ W1)   (f16, MFMA)
    k_gemm<false><<<gblk, 256, 0, stream>>>(x, W1, W1, 128, dis, bufA, N, ngroups);
    // h = relu(dis . (F'1[i] + sum F'1[src]) + b1)   (f16)
    k_agg<true><<<AGG_BLOCKS, 256, 0, stream>>>(bufA, dis, nsp, srcs,
                                                b1, b1, bufB, bufB,
                                                nullptr, nullptr, N);
    // F'2 = dis . (h @ [Wmu|Wlv])   (f16, MFMA)
    k_gemm<true><<<gblk, 256, 0, stream>>>(bufB, Wmu, Wlv, 64, dis, bufA, N, ngroups);
    // mu/lv = dis . (F'2[i] + sum F'2[src]) + b ; z fused in-wave
    k_agg<false><<<AGG_BLOCKS, 256, 0, stream>>>(bufA, dis, nsp, srcs,
                                                 bmu, blv, muo, lvo,
                                                 eps, zo, N);
}

// Round 4
// 404.478 us; speedup vs baseline: 2.4236x; 2.4236x over previous
//
#include <hip/hip_runtime.h>
#include <math.h>

// VGAE forward: 3x GCNConv + reparameterize.
// Pipeline: bucket-sort CSR build (bhist/bscan/bucket/fill2) -> MFMA GEMM1
//           (dis-scaled, f16 out) -> agg1(+b1,relu,f16) -> MFMA GEMM2
//           (W_mu|W_lv fused, dis-scaled, f16) -> agg2 (f32 + fused z).
// R4: scatter-free bucket-sort CSR build. R5: MFMA GEMM, W in VGPR B-frags.
// R6: k_bucket de-spilled; k_agg 16B-lane gather (16 lanes x f16x8 per row,
//     4 edges/trip); k_final fused into agg2 (NT stores).
// R7 (REVERTED): segment-blocked agg was 4.4x slower — counters showed the
//     HBM fetch floor is ~8 XCD x |F| = 205MB regardless of blocking (random
//     sources), and 1-edge-per-trip serial gathers killed ILP/TLP. The R6
//     agg at 2.78 TB/s combined is near the random-256B DRAM ceiling.
// R8: R6 agg + 16-edge main loop (4 outstanding 1KB gathers/wave);
//     recs packed int2->int ((row<<9)|(col&511)) halving bucket write +
//     fill2 read traffic.

#define SHIFT 9            // nodes per bucket = 512
#define EPB 2048           // edges per k_bucket block
#define HEPB 8192          // edges per k_bhist block
#define CAP 15104          // fill2 LDS srcs capacity (avg bucket = 8192)

using f32x4 = __attribute__((ext_vector_type(4))) float;
using f32x2 = __attribute__((ext_vector_type(2))) float;
using f16x8 = __attribute__((ext_vector_type(8))) _Float16;
using f16x2 = __attribute__((ext_vector_type(2))) _Float16;

// Block-wide (256 thr) exclusive scan of one int per thread.
__device__ inline int scan256(int v, int* wsum) {
    __syncthreads();  // protect wsum reuse across calls
    int lane = threadIdx.x & 63, wid = threadIdx.x >> 6;
    int s = v;
#pragma unroll
    for (int d = 1; d < 64; d <<= 1) {
        int u = __shfl_up(s, d, 64);
        if (lane >= d) s += u;
    }
    if (lane == 63) wsum[wid] = s;
    __syncthreads();
    int off = 0;
    for (int w = 0; w < wid; w++) off += wsum[w];
    return off + s - v;
}

// Per-block LDS histogram of bucket ids -> global bucket histogram.
__global__ __launch_bounds__(256) void k_bhist(const int* __restrict__ coli,
                                               int* __restrict__ gbh,
                                               int E, int NB) {
    __shared__ int lh[4][256];
    int t = threadIdx.x, w = t >> 6;
    lh[0][t] = 0; lh[1][t] = 0; lh[2][t] = 0; lh[3][t] = 0;
    __syncthreads();
    int base = blockIdx.x * HEPB;
    for (int i = t; i < HEPB; i += 256) {
        int e = base + i;
        if (e < E) atomicAdd(&lh[w][coli[e] >> SHIFT], 1);
    }
    __syncthreads();
    if (t < NB) {
        int v = lh[0][t] + lh[1][t] + lh[2][t] + lh[3][t];
        if (v) atomicAdd(&gbh[t], v);
    }
}

// One block: scan bucket sums -> bucketptr + cursors; rowptr[N]=E.
__global__ __launch_bounds__(256) void k_bscan(const int* __restrict__ gbh,
                                               int* __restrict__ bptr,
                                               int* __restrict__ bcur,
                                               int NB, int E,
                                               int* __restrict__ rowptr, int N) {
    __shared__ int wsum[4];
    int t = threadIdx.x;
    int v = (t < NB) ? gbh[t] : 0;
    int e = scan256(v, wsum);
    if (t < NB) { bptr[t] = e; bcur[t] = e; }
    if (t == 0) { bptr[NB] = E; rowptr[N] = E; }
}

// Bin EPB edges into LDS by bucket, burst-write packed (row<<9)|(col&511)
// records to contiguous per-bucket runs. Two passes over the (L2-hot) chunk;
// per-wave histograms + cursors (4x) cut LDS-atomic contention.
__global__ __launch_bounds__(256) void k_bucket(const int* __restrict__ rowi,
                                                const int* __restrict__ coli,
                                                int* __restrict__ bcur,
                                                int* __restrict__ recs,
                                                int E, int NB) {
    __shared__ int lh[4][256], lcur[4][256], excl[256], gbase[256], wsum[4];
    __shared__ int2 stage[EPB];
    int t = threadIdx.x, w = t >> 6;
    lh[0][t] = 0; lh[1][t] = 0; lh[2][t] = 0; lh[3][t] = 0;
    __syncthreads();
    int base = blockIdx.x * EPB;
    int nE = min(EPB, E - base);
    // pass A: per-wave histogram
    for (int i = t; i < nE; i += 256)
        atomicAdd(&lh[w][coli[base + i] >> SHIFT], 1);
    __syncthreads();
    int h0 = lh[0][t], h1 = lh[1][t], h2 = lh[2][t], h3 = lh[3][t];
    int tot = h0 + h1 + h2 + h3;
    int ex = scan256(tot, wsum);
    excl[t] = ex;
    lcur[0][t] = ex;
    lcur[1][t] = ex + h0;
    lcur[2][t] = ex + h0 + h1;
    lcur[3][t] = ex + h0 + h1 + h2;
    if (t < NB && tot) gbase[t] = atomicAdd(&bcur[t], tot);
    __syncthreads();
    // pass B: re-read (L2-hot) and scatter into LDS stage, per-wave cursors
    for (int i = t; i < nE; i += 256) {
        int r = rowi[base + i], c = coli[base + i];
        int p = atomicAdd(&lcur[w][c >> SHIFT], 1);
        stage[p] = make_int2(r, c);
    }
    __syncthreads();
    // pass C: coalesced burst write per bucket run (packed)
    for (int i = t; i < nE; i += 256) {
        int2 r = stage[i];
        int bb = r.y >> SHIFT;
        recs[gbase[bb] + (i - excl[bb])] = (r.x << SHIFT) | (r.y & 511);
    }
}

// One block per bucket: local histogram -> rowptr/dis, LDS scatter of rows,
// coalesced burst write of srcs. recs are packed (row<<9)|(col&511).
__global__ __launch_bounds__(256) void k_fill2(const int* __restrict__ recs,
                                               const int* __restrict__ bptr,
                                               int* __restrict__ rowptr,
                                               float* __restrict__ dis,
                                               int* __restrict__ srcs, int N) {
    __shared__ int hist[512], excl[512], wsum[4];
    __shared__ int srcsL[CAP];
    int t = threadIdx.x;
    int b = blockIdx.x;
    int nbase = b << SHIFT;
    int start = bptr[b], end = bptr[b + 1];
    int cnt = end - start;
    hist[t] = 0;
    hist[t + 256] = 0;
    __syncthreads();
    for (int i = start + t; i < end; i += 256)
        atomicAdd(&hist[recs[i] & 511], 1);
    __syncthreads();
    int h0 = hist[2 * t], h1 = hist[2 * t + 1];
    int e0 = scan256(h0 + h1, wsum);
    excl[2 * t] = e0;
    excl[2 * t + 1] = e0 + h0;
    int n0 = nbase + 2 * t, n1 = nbase + 2 * t + 1;
    if (n0 < N) { rowptr[n0] = start + e0;      dis[n0] = rsqrtf((float)(h0 + 1)); }
    if (n1 < N) { rowptr[n1] = start + e0 + h0; dis[n1] = rsqrtf((float)(h1 + 1)); }
    __syncthreads();
    if (cnt <= CAP) {
        for (int i = start + t; i < end; i += 256) {
            int r = recs[i];
            int p = atomicAdd(&excl[r & 511], 1);
            srcsL[p] = ((unsigned)r) >> SHIFT;
        }
        __syncthreads();
        for (int i = t; i < cnt; i += 256) srcs[start + i] = srcsL[i];
    } else {  // pathological bucket: direct scatter (correct, slow)
        for (int i = start + t; i < end; i += 256) {
            int r = recs[i];
            int p = atomicAdd(&excl[r & 511], 1);
            srcs[start + p] = ((unsigned)r) >> SHIFT;
        }
    }
}

// Y[M,128] = dis[row] * (X[M,128] @ W[128,128]) -> f16, via MFMA 16x16x32.
// W cols [0,split) from Wa (f32, row stride split), [split,128) from Wb.
// W staged swizzled in LDS then hoisted into 32 f16x8 VGPR B-frags.
// Verified layouts (learn_hip m89/m120):
//   A[m=lane&15][k=quad*8+j], B[k=quad*8+j][n=lane&15],
//   C/D col=lane&15 row=quad*4+reg.
template <bool XF16>
__global__ __launch_bounds__(256) void k_gemm(const void* __restrict__ Xv,
                                              const float* __restrict__ Wa,
                                              const float* __restrict__ Wb,
                                              int split,
                                              const float* __restrict__ dis,
                                              _Float16* __restrict__ Y,
                                              int M, int ngroups) {
    __shared__ _Float16 Wl[16384];  // 32 KB swizzled
    int tid = threadIdx.x;
    int wbs = 128 - split;
    for (int i = tid; i < 16384; i += 256) {
        int k = i >> 7, n = i & 127;
        float v = (n < split) ? Wa[k * split + n] : Wb[k * wbs + (n - split)];
        int tt = n >> 4, c = (k >> 5), q = (k >> 3) & 3, ln = q * 16 + (n & 15);
        Wl[(((tt * 4 + c) * 64) + ln) * 8 + (k & 7)] = (_Float16)v;
    }
    __syncthreads();

    int lane = tid & 63, w = tid >> 6;
    f16x8 B[32];
#pragma unroll
    for (int i = 0; i < 32; i++)
        B[i] = *(const f16x8*)&Wl[(i * 64 + lane) * 8];

    int m16 = lane & 15, quad = lane >> 4;
    for (int g = blockIdx.x; g < ngroups; g += gridDim.x) {
        int rowbase = g * 64 + w * 16;
        if (rowbase >= M) continue;
        int arow = min(rowbase + m16, M - 1);
        f16x8 A[4];
        if (XF16) {
            const _Float16* X = (const _Float16*)Xv;
#pragma unroll
            for (int c = 0; c < 4; c++)
                A[c] = *(const f16x8*)&X[arow * 128 + c * 32 + quad * 8];
        } else {
            const float* X = (const float*)Xv;
#pragma unroll
            for (int c = 0; c < 4; c++) {
                float4 u0 = *(const float4*)&X[arow * 128 + c * 32 + quad * 8];
                float4 u1 = *(const float4*)&X[arow * 128 + c * 32 + quad * 8 + 4];
                f16x8 a;
                a[0] = (_Float16)u0.x; a[1] = (_Float16)u0.y;
                a[2] = (_Float16)u0.z; a[3] = (_Float16)u0.w;
                a[4] = (_Float16)u1.x; a[5] = (_Float16)u1.y;
                a[6] = (_Float16)u1.z; a[7] = (_Float16)u1.w;
                A[c] = a;
            }
        }

        f32x4 acc[8];
#pragma unroll
        for (int t = 0; t < 8; t++) acc[t] = (f32x4)(0.f);
#pragma unroll
        for (int t = 0; t < 8; t++)
#pragma unroll
            for (int c = 0; c < 4; c++)
                acc[t] = __builtin_amdgcn_mfma_f32_16x16x32_f16(
                    A[c], B[t * 4 + c], acc[t], 0, 0, 0);

#pragma unroll
        for (int r = 0; r < 4; r++) {
            int row = rowbase + quad * 4 + r;
            if (row < M) {
                float d = dis[row];
#pragma unroll
                for (int t = 0; t < 8; t++)
                    Y[row * 128 + t * 16 + m16] = (_Float16)(d * acc[t][r]);
            }
        }
    }
}

// F is dis-prescaled f16 [N,128]. out[i] = bias + dis_i * (F[i] + sum F[src]).
// One wave per node; 16 lanes x f16x8 (16B) cover a row; the wave's 4
// lane-groups process 4 edges per trip (1KB/VMEM), main loop 16 edges deep
// (4 outstanding gathers/wave). Group partials combined by shfl_xor (16,32).
// OF16: output f16 [N,128] with relu (layer 1).
// else: mu->outA, lv->outB (f32 [N,64]) + fused z = mu+eps*exp(.5*lv).
template <bool OF16>
__global__ __launch_bounds__(256) void k_agg(const _Float16* __restrict__ F,
                                             const float* __restrict__ dis,
                                             const int* __restrict__ rowptr,
                                             const int* __restrict__ srcs,
                                             const float* __restrict__ ba,
                                             const float* __restrict__ bb,
                                             void* __restrict__ outA,
                                             void* __restrict__ outB,
                                             const float* __restrict__ eps,
                                             float* __restrict__ z, int N) {
    int node = blockIdx.x * 4 + (threadIdx.x >> 6);
    if (node >= N) return;
    int lane = threadIdx.x & 63;
    int g = lane >> 4, sl = lane & 15;
    const f16x8* Fr = (const f16x8*)F;   // row r chunk c at Fr[r*16 + c]

    float acc[8];
#pragma unroll
    for (int j = 0; j < 8; j++) acc[j] = 0.f;
    if (g == 0) {  // self term (F already dis-prescaled)
        f16x8 v = Fr[node * 16 + sl];
#pragma unroll
        for (int j = 0; j < 8; j++) acc[j] = (float)v[j];
    }

    int s = rowptr[node], e = rowptr[node + 1];
    int t = s;
    for (; t + 16 <= e; t += 16) {
        int i0 = srcs[t + g];
        int i1 = srcs[t + 4 + g];
        int i2 = srcs[t + 8 + g];
        int i3 = srcs[t + 12 + g];
        f16x8 v0 = Fr[i0 * 16 + sl];
        f16x8 v1 = Fr[i1 * 16 + sl];
        f16x8 v2 = Fr[i2 * 16 + sl];
        f16x8 v3 = Fr[i3 * 16 + sl];
#pragma unroll
        for (int j = 0; j < 8; j++)
            acc[j] += ((float)v0[j] + (float)v1[j]) +
                      ((float)v2[j] + (float)v3[j]);
    }
    if (t + 8 <= e) {
        int i0 = srcs[t + g];
        int i1 = srcs[t + 4 + g];
        f16x8 v0 = Fr[i0 * 16 + sl];
        f16x8 v1 = Fr[i1 * 16 + sl];
#pragma unroll
        for (int j = 0; j < 8; j++)
            acc[j] += (float)v0[j] + (float)v1[j];
        t += 8;
    }
    if (t + 4 <= e) {
        int i0 = srcs[t + g];
        f16x8 v0 = Fr[i0 * 16 + sl];
#pragma unroll
        for (int j = 0; j < 8; j++) acc[j] += (float)v0[j];
        t += 4;
    }
    if (t < e) {  // masked tail: 1..3 edges
        int idx = t + g;
        bool ok = idx < e;
        int i0 = ok ? srcs[idx] : 0;
        f16x8 v0 = Fr[i0 * 16 + sl];
        if (ok) {
#pragma unroll
            for (int j = 0; j < 8; j++) acc[j] += (float)v0[j];
        }
    }

    // butterfly reduce over the 4 lane-groups (all lanes end with full sum)
#pragma unroll
    for (int j = 0; j < 8; j++) {
        acc[j] += __shfl_xor(acc[j], 16);
        acc[j] += __shfl_xor(acc[j], 32);
    }

    float di = dis[node];
    if constexpr (OF16) {
        float4 b0 = *(const float4*)&ba[sl * 8];
        float4 b1 = *(const float4*)&ba[sl * 8 + 4];
        if (lane < 16) {
            f16x8 o;
            o[0] = (_Float16)fmaxf(fmaf(di, acc[0], b0.x), 0.f);
            o[1] = (_Float16)fmaxf(fmaf(di, acc[1], b0.y), 0.f);
            o[2] = (_Float16)fmaxf(fmaf(di, acc[2], b0.z), 0.f);
            o[3] = (_Float16)fmaxf(fmaf(di, acc[3], b0.w), 0.f);
            o[4] = (_Float16)fmaxf(fmaf(di, acc[4], b1.x), 0.f);
            o[5] = (_Float16)fmaxf(fmaf(di, acc[5], b1.y), 0.f);
            o[6] = (_Float16)fmaxf(fmaf(di, acc[6], b1.z), 0.f);
            o[7] = (_Float16)fmaxf(fmaf(di, acc[7], b1.w), 0.f);
            ((f16x8*)outA)[node * 16 + sl] = o;
        }
    } else {
        // lanes (sl<8): mu cols sl*8..+7 ; lanes (sl>=8): lv cols (sl-8)*8..+7
        const float* bp = (sl < 8) ? ba : bb;
        int cb = (sl & 7) * 8;
        float4 b0 = *(const float4*)&bp[cb];
        float4 b1 = *(const float4*)&bp[cb + 4];
        float o[8];
        o[0] = fmaf(di, acc[0], b0.x);
        o[1] = fmaf(di, acc[1], b0.y);
        o[2] = fmaf(di, acc[2], b0.z);
        o[3] = fmaf(di, acc[3], b0.w);
        o[4] = fmaf(di, acc[4], b1.x);
        o[5] = fmaf(di, acc[5], b1.y);
        o[6] = fmaf(di, acc[6], b1.z);
        o[7] = fmaf(di, acc[7], b1.w);
        if (lane < 16) {
            float* op = (sl < 8) ? (float*)outA : (float*)outB;
            f32x4 s0, s1;
            s0[0] = o[0]; s0[1] = o[1]; s0[2] = o[2]; s0[3] = o[3];
            s1[0] = o[4]; s1[1] = o[5]; s1[2] = o[6]; s1[3] = o[7];
            __builtin_nontemporal_store(s0, (f32x4*)&op[node * 64 + cb]);
            __builtin_nontemporal_store(s1, (f32x4*)&op[node * 64 + cb + 4]);
        }
        // fused reparameterize: lane l (<8) pulls lv chunk from lane l+8
        float lvv[8];
#pragma unroll
        for (int j = 0; j < 8; j++) lvv[j] = __shfl_xor(o[j], 8);
        if (lane < 8) {
            int zb = node * 64 + sl * 8;
            float4 e0 = *(const float4*)&eps[zb];
            float4 e1 = *(const float4*)&eps[zb + 4];
            f32x4 z0, z1;
            z0[0] = fmaf(e0.x, expf(0.5f * lvv[0]), o[0]);
            z0[1] = fmaf(e0.y, expf(0.5f * lvv[1]), o[1]);
            z0[2] = fmaf(e0.z, expf(0.5f * lvv[2]), o[2]);
            z0[3] = fmaf(e0.w, expf(0.5f * lvv[3]), o[3]);
            z1[0] = fmaf(e1.x, expf(0.5f * lvv[4]), o[4]);
            z1[1] = fmaf(e1.y, expf(0.5f * lvv[5]), o[5]);
            z1[2] = fmaf(e1.z, expf(0.5f * lvv[6]), o[6]);
            z1[3] = fmaf(e1.w, expf(0.5f * lvv[7]), o[7]);
            __builtin_nontemporal_store(z0, (f32x4*)&z[zb]);
            __builtin_nontemporal_store(z1, (f32x4*)&z[zb + 4]);
        }
    }
}

extern "C" void kernel_launch(void* const* d_in, const int* in_sizes, int n_in,
                              void* d_out, int out_size, void* d_ws, size_t ws_size,
                              hipStream_t stream) {
    const float* x   = (const float*)d_in[0];
    const int*   ei  = (const int*)d_in[1];
    const float* W1  = (const float*)d_in[2];
    const float* b1  = (const float*)d_in[3];
    const float* Wmu = (const float*)d_in[4];
    const float* bmu = (const float*)d_in[5];
    const float* Wlv = (const float*)d_in[6];
    const float* blv = (const float*)d_in[7];
    const float* eps = (const float*)d_in[8];

    int N = in_sizes[0] / 128;   // 100000
    int E = in_sizes[1] / 2;     // 1600000
    const int* rowi = ei;        // edge_index[0]
    const int* coli = ei + E;    // edge_index[1]
    int NB = (N + (1 << SHIFT) - 1) >> SHIFT;   // 196 buckets

    char* ws = (char*)d_ws;
    size_t off = 0;
    auto alloc = [&](size_t bytes) -> void* {
        void* p = ws + off;
        off += (bytes + 255) & ~(size_t)255;
        return p;
    };
    _Float16* bufA = (_Float16*)alloc((size_t)N * 128 * 2);  // F'1, F'2
    _Float16* bufB = (_Float16*)alloc((size_t)N * 128 * 2);  // h (f16)
    float* dis    = (float*)alloc((size_t)N * 4);
    int*   rowptr = (int*)alloc((size_t)(N + 1) * 4);
    int*   srcs   = (int*)alloc((size_t)E * 4);
    int*   recs   = (int*)alloc((size_t)E * 4);   // packed (row<<9)|(col&511)
    int*   bhist  = (int*)alloc((size_t)NB * 4);
    int*   bptr   = (int*)alloc((size_t)(NB + 1) * 4);
    int*   bcur   = (int*)alloc((size_t)NB * 4);

    float* zo  = (float*)d_out;                 // [N,64]
    float* muo = zo + (size_t)N * 64;           // [N,64]
    float* lvo = zo + (size_t)N * 128;          // [N,64]

    hipMemsetAsync(bhist, 0, (size_t)NB * 4, stream);
    k_bhist<<<(E + HEPB - 1) / HEPB, 256, 0, stream>>>(coli, bhist, E, NB);
    k_bscan<<<1, 256, 0, stream>>>(bhist, bptr, bcur, NB, E, rowptr, N);
    k_bucket<<<(E + EPB - 1) / EPB, 256, 0, stream>>>(rowi, coli, bcur, recs, E, NB);
    k_fill2<<<NB, 256, 0, stream>>>(recs, bptr, rowptr, dis, srcs, N);

    int ngroups = (N + 63) / 64;
    int gblk = ngroups < 640 ? ngroups : 640;
    // F'1 = dis . (x @ W1)   (f16, MFMA)
    k_gemm<false><<<gblk, 256, 0, stream>>>(x, W1, W1, 128, dis, bufA, N, ngroups);
    // h = relu(dis . (F'1[i] + sum F'1[src]) + b1)   (f16)
    k_agg<true><<<(N + 3) / 4, 256, 0, stream>>>(bufA, dis, rowptr, srcs,
                                                 b1, b1, bufB, bufB,
                                                 nullptr, nullptr, N);
    // F'2 = dis . (h @ [Wmu|Wlv])   (f16, MFMA)
    k_gemm<true><<<gblk, 256, 0, stream>>>(bufB, Wmu, Wlv, 64, dis, bufA, N, ngroups);
    // mu/lv = dis . (F'2[i] + sum F'2[src]) + b ; z fused in-wave
    k_agg<false><<<(N + 3) / 4, 256, 0, stream>>>(bufA, dis, rowptr, srcs,
                                                  bmu, blv, muo, lvo,
                                                  eps, zo, N);
}

// Round 5
// 381.503 us; speedup vs baseline: 2.5696x; 1.0602x over previous
//
#include <hip/hip_runtime.h>
#include <math.h>

// VGAE forward: 3x GCNConv + reparameterize.
// Pipeline (6 dispatches): MFMA GEMM1 (zeroes bcur) -> bucket-sort CSR build
//   (k_bucket fixed-stride + k_fill2) -> agg1(+b1,relu,f16) -> MFMA GEMM2
//   (W_mu|W_lv fused) -> agg2 (f32 mu/lv + fused z).
// R4: scatter-free bucket-sort CSR build. R5: MFMA GEMM, W in VGPR B-frags.
// R6: k_bucket de-spilled; k_agg 16B-lane gather (16 lanes x f16x8 per row,
//     4 edges/trip, 16-deep main loop); k_final fused into agg2 (NT stores).
// R7 (REVERTED): segment-blocked agg 4.4x slower — HBM fetch floor is
//     ~8 XCD x |F| = 205MB regardless of blocking; agg<0> measured AT that
//     floor (203MB) at 3.33 TB/s = random-256B ceiling. Aggs are roofline.
// R8: packed recs; 16-deep gather loop.
// R9: dispatch-count attack (9 -> 6): ~170us of total was unexplained by
//     kernel sums => launch overhead. Dropped k_bhist/k_bscan/memset via
//     fixed-stride buckets (atomic cursors, no global scan; rowse int2
//     absolute spans). dis-prescale moved out of GEMMs into per-edge fma in
//     agg (dis is L2-resident 400KB; add->fma is VALU-neutral) so GEMM1 is
//     CSR-independent, runs first, and zeroes bcur (replaces memset).

#define SHIFT 9            // nodes per bucket = 512
#define EPB 2048           // edges per k_bucket block
#define BSTRIDE 12288      // recs/srcs slots per bucket (1.5x Poisson mean)
#define CAP 15104          // fill2 LDS srcs capacity

using f32x4 = __attribute__((ext_vector_type(4))) float;
using f32x2 = __attribute__((ext_vector_type(2))) float;
using f16x8 = __attribute__((ext_vector_type(8))) _Float16;
using f16x2 = __attribute__((ext_vector_type(2))) _Float16;

// Block-wide (256 thr) exclusive scan of one int per thread.
__device__ inline int scan256(int v, int* wsum) {
    __syncthreads();  // protect wsum reuse across calls
    int lane = threadIdx.x & 63, wid = threadIdx.x >> 6;
    int s = v;
#pragma unroll
    for (int d = 1; d < 64; d <<= 1) {
        int u = __shfl_up(s, d, 64);
        if (lane >= d) s += u;
    }
    if (lane == 63) wsum[wid] = s;
    __syncthreads();
    int off = 0;
    for (int w = 0; w < wid; w++) off += wsum[w];
    return off + s - v;
}

// Bin EPB edges into LDS by bucket, burst-write packed (row<<9)|(col&511)
// records into the bucket's fixed-stride region (base = b*BSTRIDE + atomic
// cursor). Two passes over the (L2-hot) chunk; per-wave histograms+cursors.
__global__ __launch_bounds__(256) void k_bucket(const int* __restrict__ rowi,
                                                const int* __restrict__ coli,
                                                int* __restrict__ bcur,
                                                int* __restrict__ recs,
                                                int E, int NB) {
    __shared__ int lh[4][256], lcur[4][256], excl[256], gbase[256], wsum[4];
    __shared__ int2 stage[EPB];
    int t = threadIdx.x, w = t >> 6;
    lh[0][t] = 0; lh[1][t] = 0; lh[2][t] = 0; lh[3][t] = 0;
    __syncthreads();
    int base = blockIdx.x * EPB;
    int nE = min(EPB, E - base);
    // pass A: per-wave histogram
    for (int i = t; i < nE; i += 256)
        atomicAdd(&lh[w][coli[base + i] >> SHIFT], 1);
    __syncthreads();
    int h0 = lh[0][t], h1 = lh[1][t], h2 = lh[2][t], h3 = lh[3][t];
    int tot = h0 + h1 + h2 + h3;
    int ex = scan256(tot, wsum);
    excl[t] = ex;
    lcur[0][t] = ex;
    lcur[1][t] = ex + h0;
    lcur[2][t] = ex + h0 + h1;
    lcur[3][t] = ex + h0 + h1 + h2;
    if (t < NB && tot)
        gbase[t] = t * BSTRIDE + atomicAdd(&bcur[t], tot);
    __syncthreads();
    // pass B: re-read (L2-hot) and scatter into LDS stage, per-wave cursors
    for (int i = t; i < nE; i += 256) {
        int r = rowi[base + i], c = coli[base + i];
        int p = atomicAdd(&lcur[w][c >> SHIFT], 1);
        stage[p] = make_int2(r, c);
    }
    __syncthreads();
    // pass C: coalesced burst write per bucket run (packed, bounds-guarded)
    for (int i = t; i < nE; i += 256) {
        int2 r = stage[i];
        int bb = r.y >> SHIFT;
        int idx = gbase[bb] + (i - excl[bb]);
        if (idx - bb * BSTRIDE < BSTRIDE)   // statistically never false
            recs[idx] = (r.x << SHIFT) | (r.y & 511);
    }
}

// One block per bucket: local histogram -> rowse (absolute spans) + dis,
// LDS scatter of rows, coalesced burst write of srcs (bucket-strided).
__global__ __launch_bounds__(256) void k_fill2(const int* __restrict__ recs,
                                               const int* __restrict__ bcur,
                                               int2* __restrict__ rowse,
                                               float* __restrict__ dis,
                                               int* __restrict__ srcs, int N) {
    __shared__ int hist[512], excl[512], wsum[4];
    __shared__ int srcsL[CAP];
    int t = threadIdx.x;
    int b = blockIdx.x;
    int nbase = b << SHIFT;
    int start = b * BSTRIDE;
    int cnt = min(bcur[b], BSTRIDE);
    int end = start + cnt;
    hist[t] = 0;
    hist[t + 256] = 0;
    __syncthreads();
    for (int i = start + t; i < end; i += 256)
        atomicAdd(&hist[recs[i] & 511], 1);
    __syncthreads();
    int h0 = hist[2 * t], h1 = hist[2 * t + 1];
    int e0 = scan256(h0 + h1, wsum);
    excl[2 * t] = e0;
    excl[2 * t + 1] = e0 + h0;
    int n0 = nbase + 2 * t, n1 = nbase + 2 * t + 1;
    if (n0 < N) {
        rowse[n0] = make_int2(start + e0, start + e0 + h0);
        dis[n0] = rsqrtf((float)(h0 + 1));
    }
    if (n1 < N) {
        rowse[n1] = make_int2(start + e0 + h0, start + e0 + h0 + h1);
        dis[n1] = rsqrtf((float)(h1 + 1));
    }
    __syncthreads();
    if (cnt <= CAP) {
        for (int i = start + t; i < end; i += 256) {
            int r = recs[i];
            int p = atomicAdd(&excl[r & 511], 1);
            srcsL[p] = ((unsigned)r) >> SHIFT;
        }
        __syncthreads();
        for (int i = t; i < cnt; i += 256) srcs[start + i] = srcsL[i];
    } else {  // pathological bucket: direct scatter (correct, slow)
        for (int i = start + t; i < end; i += 256) {
            int r = recs[i];
            int p = atomicAdd(&excl[r & 511], 1);
            srcs[start + p] = ((unsigned)r) >> SHIFT;
        }
    }
}

// Y[M,128] = X[M,128] @ W[128,128] -> f16 (UNSCALED), via MFMA 16x16x32.
// W cols [0,split) from Wa (f32, row stride split), [split,128) from Wb.
// W staged swizzled in LDS then hoisted into 32 f16x8 VGPR B-frags.
// If zcur != nullptr, block 0 zeroes zcur[0..nz) (replaces a memset launch;
// this kernel runs before k_bucket in the stream).
// Verified layouts (learn_hip m89/m120):
//   A[m=lane&15][k=quad*8+j], B[k=quad*8+j][n=lane&15],
//   C/D col=lane&15 row=quad*4+reg.
template <bool XF16>
__global__ __launch_bounds__(256) void k_gemm(const void* __restrict__ Xv,
                                              const float* __restrict__ Wa,
                                              const float* __restrict__ Wb,
                                              int split,
                                              _Float16* __restrict__ Y,
                                              int M, int ngroups,
                                              int* __restrict__ zcur, int nz) {
    __shared__ _Float16 Wl[16384];  // 32 KB swizzled
    int tid = threadIdx.x;
    if (zcur && blockIdx.x == 0 && tid < nz) zcur[tid] = 0;
    int wbs = 128 - split;
    for (int i = tid; i < 16384; i += 256) {
        int k = i >> 7, n = i & 127;
        float v = (n < split) ? Wa[k * split + n] : Wb[k * wbs + (n - split)];
        int tt = n >> 4, c = (k >> 5), q = (k >> 3) & 3, ln = q * 16 + (n & 15);
        Wl[(((tt * 4 + c) * 64) + ln) * 8 + (k & 7)] = (_Float16)v;
    }
    __syncthreads();

    int lane = tid & 63, w = tid >> 6;
    f16x8 B[32];
#pragma unroll
    for (int i = 0; i < 32; i++)
        B[i] = *(const f16x8*)&Wl[(i * 64 + lane) * 8];

    int m16 = lane & 15, quad = lane >> 4;
    for (int g = blockIdx.x; g < ngroups; g += gridDim.x) {
        int rowbase = g * 64 + w * 16;
        if (rowbase >= M) continue;
        int arow = min(rowbase + m16, M - 1);
        f16x8 A[4];
        if (XF16) {
            const _Float16* X = (const _Float16*)Xv;
#pragma unroll
            for (int c = 0; c < 4; c++)
                A[c] = *(const f16x8*)&X[arow * 128 + c * 32 + quad * 8];
        } else {
            const float* X = (const float*)Xv;
#pragma unroll
            for (int c = 0; c < 4; c++) {
                float4 u0 = *(const float4*)&X[arow * 128 + c * 32 + quad * 8];
                float4 u1 = *(const float4*)&X[arow * 128 + c * 32 + quad * 8 + 4];
                f16x8 a;
                a[0] = (_Float16)u0.x; a[1] = (_Float16)u0.y;
                a[2] = (_Float16)u0.z; a[3] = (_Float16)u0.w;
                a[4] = (_Float16)u1.x; a[5] = (_Float16)u1.y;
                a[6] = (_Float16)u1.z; a[7] = (_Float16)u1.w;
                A[c] = a;
            }
        }

        f32x4 acc[8];
#pragma unroll
        for (int t = 0; t < 8; t++) acc[t] = (f32x4)(0.f);
#pragma unroll
        for (int t = 0; t < 8; t++)
#pragma unroll
            for (int c = 0; c < 4; c++)
                acc[t] = __builtin_amdgcn_mfma_f32_16x16x32_f16(
                    A[c], B[t * 4 + c], acc[t], 0, 0, 0);

#pragma unroll
        for (int r = 0; r < 4; r++) {
            int row = rowbase + quad * 4 + r;
            if (row < M) {
#pragma unroll
                for (int t = 0; t < 8; t++)
                    Y[row * 128 + t * 16 + m16] = (_Float16)acc[t][r];
            }
        }
    }
}

// F is UNSCALED f16 [N,128]. out[i] = b + dis_i*(dis_i*F[i] + sum dis_s*F[s]).
// One wave per node; 16 lanes x f16x8 (16B) cover a row; the wave's 4
// lane-groups process 4 edges per trip (1KB/VMEM), main loop 16 edges deep.
// dis[src] applied per-edge (fma — VALU-neutral vs add; dis is L2-resident).
// Group partials combined by shfl_xor butterfly (16,32).
// OF16: output f16 [N,128] with relu (layer 1).
// else: mu->outA, lv->outB (f32 [N,64]) + fused z = mu+eps*exp(.5*lv).
template <bool OF16>
__global__ __launch_bounds__(256) void k_agg(const _Float16* __restrict__ F,
                                             const float* __restrict__ dis,
                                             const int2* __restrict__ rowse,
                                             const int* __restrict__ srcs,
                                             const float* __restrict__ ba,
                                             const float* __restrict__ bb,
                                             void* __restrict__ outA,
                                             void* __restrict__ outB,
                                             const float* __restrict__ eps,
                                             float* __restrict__ z, int N) {
    int node = blockIdx.x * 4 + (threadIdx.x >> 6);
    if (node >= N) return;
    int lane = threadIdx.x & 63;
    int g = lane >> 4, sl = lane & 15;
    const f16x8* Fr = (const f16x8*)F;   // row r chunk c at Fr[r*16 + c]

    float di = dis[node];
    float acc[8];
#pragma unroll
    for (int j = 0; j < 8; j++) acc[j] = 0.f;
    if (g == 0) {  // self term: dis_i * F[i]
        f16x8 v = Fr[node * 16 + sl];
#pragma unroll
        for (int j = 0; j < 8; j++) acc[j] = di * (float)v[j];
    }

    int2 se = rowse[node];
    int s = se.x, e = se.y;
    int t = s;
    for (; t + 16 <= e; t += 16) {
        int i0 = srcs[t + g];
        int i1 = srcs[t + 4 + g];
        int i2 = srcs[t + 8 + g];
        int i3 = srcs[t + 12 + g];
        float d0 = dis[i0], d1 = dis[i1], d2 = dis[i2], d3 = dis[i3];
        f16x8 v0 = Fr[i0 * 16 + sl];
        f16x8 v1 = Fr[i1 * 16 + sl];
        f16x8 v2 = Fr[i2 * 16 + sl];
        f16x8 v3 = Fr[i3 * 16 + sl];
#pragma unroll
        for (int j = 0; j < 8; j++)
            acc[j] = fmaf(d0, (float)v0[j],
                     fmaf(d1, (float)v1[j],
                     fmaf(d2, (float)v2[j],
                     fmaf(d3, (float)v3[j], acc[j]))));
    }
    if (t + 8 <= e) {
        int i0 = srcs[t + g];
        int i1 = srcs[t + 4 + g];
        float d0 = dis[i0], d1 = dis[i1];
        f16x8 v0 = Fr[i0 * 16 + sl];
        f16x8 v1 = Fr[i1 * 16 + sl];
#pragma unroll
        for (int j = 0; j < 8; j++)
            acc[j] = fmaf(d0, (float)v0[j], fmaf(d1, (float)v1[j], acc[j]));
        t += 8;
    }
    if (t + 4 <= e) {
        int i0 = srcs[t + g];
        float d0 = dis[i0];
        f16x8 v0 = Fr[i0 * 16 + sl];
#pragma unroll
        for (int j = 0; j < 8; j++) acc[j] = fmaf(d0, (float)v0[j], acc[j]);
        t += 4;
    }
    if (t < e) {  // masked tail: 1..3 edges
        int idx = t + g;
        bool ok = idx < e;
        int i0 = ok ? srcs[idx] : 0;
        float d0 = dis[i0];
        f16x8 v0 = Fr[i0 * 16 + sl];
        if (ok) {
#pragma unroll
            for (int j = 0; j < 8; j++) acc[j] = fmaf(d0, (float)v0[j], acc[j]);
        }
    }

    // butterfly reduce over the 4 lane-groups (all lanes end with full sum)
#pragma unroll
    for (int j = 0; j < 8; j++) {
        acc[j] += __shfl_xor(acc[j], 16);
        acc[j] += __shfl_xor(acc[j], 32);
    }

    if constexpr (OF16) {
        float4 b0 = *(const float4*)&ba[sl * 8];
        float4 b1 = *(const float4*)&ba[sl * 8 + 4];
        if (lane < 16) {
            f16x8 o;
            o[0] = (_Float16)fmaxf(fmaf(di, acc[0], b0.x), 0.f);
            o[1] = (_Float16)fmaxf(fmaf(di, acc[1], b0.y), 0.f);
            o[2] = (_Float16)fmaxf(fmaf(di, acc[2], b0.z), 0.f);
            o[3] = (_Float16)fmaxf(fmaf(di, acc[3], b0.w), 0.f);
            o[4] = (_Float16)fmaxf(fmaf(di, acc[4], b1.x), 0.f);
            o[5] = (_Float16)fmaxf(fmaf(di, acc[5], b1.y), 0.f);
            o[6] = (_Float16)fmaxf(fmaf(di, acc[6], b1.z), 0.f);
            o[7] = (_Float16)fmaxf(fmaf(di, acc[7], b1.w), 0.f);
            ((f16x8*)outA)[node * 16 + sl] = o;
        }
    } else {
        // lanes (sl<8): mu cols sl*8..+7 ; lanes (sl>=8): lv cols (sl-8)*8..+7
        const float* bp = (sl < 8) ? ba : bb;
        int cb = (sl & 7) * 8;
        float4 b0 = *(const float4*)&bp[cb];
        float4 b1 = *(const float4*)&bp[cb + 4];
        float o[8];
        o[0] = fmaf(di, acc[0], b0.x);
        o[1] = fmaf(di, acc[1], b0.y);
        o[2] = fmaf(di, acc[2], b0.z);
        o[3] = fmaf(di, acc[3], b0.w);
        o[4] = fmaf(di, acc[4], b1.x);
        o[5] = fmaf(di, acc[5], b1.y);
        o[6] = fmaf(di, acc[6], b1.z);
        o[7] = fmaf(di, acc[7], b1.w);
        if (lane < 16) {
            float* op = (sl < 8) ? (float*)outA : (float*)outB;
            f32x4 s0, s1;
            s0[0] = o[0]; s0[1] = o[1]; s0[2] = o[2]; s0[3] = o[3];
            s1[0] = o[4]; s1[1] = o[5]; s1[2] = o[6]; s1[3] = o[7];
            __builtin_nontemporal_store(s0, (f32x4*)&op[node * 64 + cb]);
            __builtin_nontemporal_store(s1, (f32x4*)&op[node * 64 + cb + 4]);
        }
        // fused reparameterize: lane l (<8) pulls lv chunk from lane l+8
        float lvv[8];
#pragma unroll
        for (int j = 0; j < 8; j++) lvv[j] = __shfl_xor(o[j], 8);
        if (lane < 8) {
            int zb = node * 64 + sl * 8;
            float4 e0 = *(const float4*)&eps[zb];
            float4 e1 = *(const float4*)&eps[zb + 4];
            f32x4 z0, z1;
            z0[0] = fmaf(e0.x, expf(0.5f * lvv[0]), o[0]);
            z0[1] = fmaf(e0.y, expf(0.5f * lvv[1]), o[1]);
            z0[2] = fmaf(e0.z, expf(0.5f * lvv[2]), o[2]);
            z0[3] = fmaf(e0.w, expf(0.5f * lvv[3]), o[3]);
            z1[0] = fmaf(e1.x, expf(0.5f * lvv[4]), o[4]);
            z1[1] = fmaf(e1.y, expf(0.5f * lvv[5]), o[5]);
            z1[2] = fmaf(e1.z, expf(0.5f * lvv[6]), o[6]);
            z1[3] = fmaf(e1.w, expf(0.5f * lvv[7]), o[7]);
            __builtin_nontemporal_store(z0, (f32x4*)&z[zb]);
            __builtin_nontemporal_store(z1, (f32x4*)&z[zb + 4]);
        }
    }
}

extern "C" void kernel_launch(void* const* d_in, const int* in_sizes, int n_in,
                              void* d_out, int out_size, void* d_ws, size_t ws_size,
                              hipStream_t stream) {
    const float* x   = (const float*)d_in[0];
    const int*   ei  = (const int*)d_in[1];
    const float* W1  = (const float*)d_in[2];
    const float* b1  = (const float*)d_in[3];
    const float* Wmu = (const float*)d_in[4];
    const float* bmu = (const float*)d_in[5];
    const float* Wlv = (const float*)d_in[6];
    const float* blv = (const float*)d_in[7];
    const float* eps = (const float*)d_in[8];

    int N = in_sizes[0] / 128;   // 100000
    int E = in_sizes[1] / 2;     // 1600000
    const int* rowi = ei;        // edge_index[0]
    const int* coli = ei + E;    // edge_index[1]
    int NB = (N + (1 << SHIFT) - 1) >> SHIFT;   // 196 buckets

    char* ws = (char*)d_ws;
    size_t off = 0;
    auto alloc = [&](size_t bytes) -> void* {
        void* p = ws + off;
        off += (bytes + 255) & ~(size_t)255;
        return p;
    };
    _Float16* bufA = (_Float16*)alloc((size_t)N * 128 * 2);  // F1, F2
    _Float16* bufB = (_Float16*)alloc((size_t)N * 128 * 2);  // h (f16)
    float* dis    = (float*)alloc((size_t)N * 4);
    int2*  rowse  = (int2*)alloc((size_t)N * 8);
    int*   srcs   = (int*)alloc((size_t)NB * BSTRIDE * 4);
    int*   recs   = (int*)alloc((size_t)NB * BSTRIDE * 4);  // packed row<<9|col
    int*   bcur   = (int*)alloc((size_t)NB * 4);

    float* zo  = (float*)d_out;                 // [N,64]
    float* muo = zo + (size_t)N * 64;           // [N,64]
    float* lvo = zo + (size_t)N * 128;          // [N,64]

    int ngroups = (N + 63) / 64;
    int gblk = ngroups < 640 ? ngroups : 640;
    // F1 = x @ W1 (f16, MFMA); also zeroes bcur for the CSR build.
    k_gemm<false><<<gblk, 256, 0, stream>>>(x, W1, W1, 128, bufA, N, ngroups,
                                            bcur, NB);
    k_bucket<<<(E + EPB - 1) / EPB, 256, 0, stream>>>(rowi, coli, bcur, recs,
                                                      E, NB);
    k_fill2<<<NB, 256, 0, stream>>>(recs, bcur, rowse, dis, srcs, N);
    // h = relu(dis_i*(dis_i*F1[i] + sum dis_s*F1[s]) + b1)   (f16)
    k_agg<true><<<(N + 3) / 4, 256, 0, stream>>>(bufA, dis, rowse, srcs,
                                                 b1, b1, bufB, bufB,
                                                 nullptr, nullptr, N);
    // F2 = h @ [Wmu|Wlv]   (f16, MFMA)
    k_gemm<true><<<gblk, 256, 0, stream>>>(bufB, Wmu, Wlv, 64, bufA, N, ngroups,
                                           nullptr, 0);
    // mu/lv = dis-weighted agg + b ; z fused in-wave
    k_agg<false><<<(N + 3) / 4, 256, 0, stream>>>(bufA, dis, rowse, srcs,
                                                  bmu, blv, muo, lvo,
                                                  eps, zo, N);
}